// Round 1
// 729.666 us; speedup vs baseline: 1.4168x; 1.4168x over previous
//
#include <hip/hip_runtime.h>
#include <math.h>

#define KP 136   // padded K stride in LDS (elements) for fallback kernel

typedef short v8s __attribute__((ext_vector_type(8)));
typedef float v4f __attribute__((ext_vector_type(4)));

// round-to-nearest-even float -> bf16 bits; also returns the bf16 value as float
__device__ __forceinline__ unsigned short bf16_rne(float f, float* back) {
    union { float f; unsigned u; } a; a.f = f;
    unsigned r = a.u + 0x7FFFu + ((a.u >> 16) & 1u);
    unsigned short h = (unsigned short)(r >> 16);
    union { unsigned u; float f; } bb; bb.u = (unsigned)h << 16;
    *back = bb.f;
    return h;
}

// ======================================================================
// NEW: two-kernel split.
//  Kernel 1 (sph_prep): compute Y once (not once per h-tile) and store
//  split-bf16 in MFMA-fragment-native chunk layout [c][P][8] (c = k/8,
//  k = c*8+e). Also converts W once into [c][1024][8] hi/lo + w128c.
//  All stores are register-buffered, fully coalesced dwordx4. No LDS.
//  Kernel 2 (sph_gemm): LDS-free, barrier-free GEMM. Fragments loaded
//  directly from global (W panel L2-resident, Y L3-resident).
//  256 threads, 64x128 tile, <=128 VGPR -> 4 blocks/CU.
// ======================================================================

__global__ __launch_bounds__(512)
void sph_prep(const float* __restrict__ x, const float* __restrict__ W,
              unsigned short* __restrict__ Yhi, unsigned short* __restrict__ Ylo,
              float* __restrict__ y128,
              unsigned short* __restrict__ Whi, unsigned short* __restrict__ Wlo,
              float* __restrict__ w128c, int P) {
    const int tid = threadIdx.x;
    const int nyb = P >> 7;                 // pixel blocks (128 pixels each)
    const int b = blockIdx.x;

    if (b < nyb) {
        // ---- Y part: thread = (pixel, segment s). Segment s covers
        // recurrence m = 16s .. 16s+16; writes pos k = 64+16s..79+16s
        // (chunks 8+2s, 9+2s) and neg k = 48-16s..63-16s (chunks 6-2s, 7-2s).
        const int pix = tid & 127;
        const int s   = tid >> 7;           // uniform per wave
        const int m0  = 16 * s;
        const int p   = b * 128 + pix;
        const float2 tp = *(const float2*)&x[(size_t)p * 2];
        const float theta = tp.x, phi = tp.y;

        const float ct = cosf(phi);
        const float st = sqrtf(fmaxf(1.0f - ct * ct, 0.0f));

        // jump-start Pbar_{m0}^{m0}
        float prod = 1.0f;
        for (int i = 1; i <= m0; ++i) prod *= (2.0f * i + 1.0f) / (2.0f * i);
        const float s2_ = st * st, s4 = s2_ * s2_, s8 = s4 * s4, s16 = s8 * s8;
        float stp = 1.0f;
        for (int i = 0; i < s; ++i) stp *= s16;
        float pm = 0.28209479177387814f * sqrtf(prod) * stp;

        float cm, sm, c1, s1;
        sincosf((float)m0 * theta, &sm, &cm);
        sincosf(theta, &s1, &c1);

        unsigned short ph[16], pl[16], nh[16], nl[16];
        float y128v = 0.0f;

        // j = 0 (m = m0): pos k = 64 + m0
        {
            const float yb = sqrtf(2.0f * m0 + 3.0f) * ct * pm;
            const float val = (s == 0) ? yb                       // m=0: no sqrt2, cos0=1
                                       : 1.4142135623730951f * yb * cm;  // m0 even -> +
            float hf, d;
            ph[0] = bf16_rne(val, &hf);
            pl[0] = bf16_rne(val - hf, &d);
        }

        #pragma unroll
        for (int j = 1; j <= 16; ++j) {
            const int m = m0 + j;
            pm *= -sqrtf((2.0f * m + 1.0f) / (2.0f * m)) * st;
            const float cn = cm * c1 - sm * s1;
            const float sn = sm * c1 + cm * s1;
            cm = cn; sm = sn;
            const float yb = sqrtf(2.0f * m + 3.0f) * ct * pm;
            const float t  = (m & 1) ? -1.4142135623730951f : 1.4142135623730951f;
            const float vp = t * yb * cm;   // k = 64 + m
            const float vn = t * yb * sm;   // k = 64 - m
            {
                float hf, d;
                nh[16 - j] = bf16_rne(vn, &hf);       // neg idx i = k-(48-16s) = 16-j
                nl[16 - j] = bf16_rne(vn - hf, &d);
            }
            if (j <= 15) {
                float hf, d;
                ph[j] = bf16_rne(vp, &hf);
                pl[j] = bf16_rne(vp - hf, &d);
            } else if (s == 3) {
                y128v = vp;                           // m = 64 -> k = 128
            }
            // (for s<3, j=16 pos value k=80+16s is produced by segment s+1's j=0)
        }

        // ---- coalesced chunk stores: addr (c*P + p)*8 elems; lanes = consecutive p
        {
            v8s vh, vl;
            #pragma unroll
            for (int e = 0; e < 8; ++e) { vh[e] = (short)ph[e]; vl[e] = (short)pl[e]; }
            *(v8s*)&Yhi[((size_t)(8 + 2 * s) * P + p) * 8] = vh;
            *(v8s*)&Ylo[((size_t)(8 + 2 * s) * P + p) * 8] = vl;
        }
        {
            v8s vh, vl;
            #pragma unroll
            for (int e = 0; e < 8; ++e) { vh[e] = (short)ph[8 + e]; vl[e] = (short)pl[8 + e]; }
            *(v8s*)&Yhi[((size_t)(9 + 2 * s) * P + p) * 8] = vh;
            *(v8s*)&Ylo[((size_t)(9 + 2 * s) * P + p) * 8] = vl;
        }
        {
            v8s vh, vl;
            #pragma unroll
            for (int e = 0; e < 8; ++e) { vh[e] = (short)nh[e]; vl[e] = (short)nl[e]; }
            *(v8s*)&Yhi[((size_t)(6 - 2 * s) * P + p) * 8] = vh;
            *(v8s*)&Ylo[((size_t)(6 - 2 * s) * P + p) * 8] = vl;
        }
        {
            v8s vh, vl;
            #pragma unroll
            for (int e = 0; e < 8; ++e) { vh[e] = (short)nh[8 + e]; vl[e] = (short)nl[8 + e]; }
            *(v8s*)&Yhi[((size_t)(7 - 2 * s) * P + p) * 8] = vh;
            *(v8s*)&Ylo[((size_t)(7 - 2 * s) * P + p) * 8] = vl;
        }
        if (s == 3) y128[p] = y128v;
    } else {
        // ---- W part: one thread per (h, c); 16384 threads = 32 blocks
        const int idx = (b - nyb) * 512 + tid;
        const int c = idx >> 10;
        const int h = idx & 1023;
        const float* wrow = W + (size_t)h * 129 + c * 8;
        v8s vh, vl;
        #pragma unroll
        for (int e = 0; e < 8; ++e) {
            const float w = wrow[e];
            float hf, d;
            vh[e] = (short)bf16_rne(w, &hf);
            vl[e] = (short)bf16_rne(w - hf, &d);
        }
        *(v8s*)&Whi[((size_t)c * 1024 + h) * 8] = vh;
        *(v8s*)&Wlo[((size_t)c * 1024 + h) * 8] = vl;
        if (idx < 1024) w128c[idx] = W[(size_t)idx * 129 + 128];
    }
}

// LDS-free GEMM: tile 64 pixels x 128 channels, 4 waves (1x4), acc 4x2.
__global__ __launch_bounds__(256, 4)
void sph_gemm(const unsigned short* __restrict__ Yhi, const unsigned short* __restrict__ Ylo,
              const float* __restrict__ y128,
              const unsigned short* __restrict__ Whi, const unsigned short* __restrict__ Wlo,
              const float* __restrict__ w128c, const float* __restrict__ bias,
              float* __restrict__ out, int P) {
    const int tid  = threadIdx.x;
    const int lane = tid & 63;
    const int wn   = tid >> 6;          // 0..3 -> 32 channels each
    const int l16  = lane & 15;
    const int quad = lane >> 4;
    const int p0 = blockIdx.x * 64;     // pixel tile origin
    const int h0 = blockIdx.y * 128;    // channel tile origin

    v4f acc[4][2];
    #pragma unroll
    for (int mt = 0; mt < 4; ++mt)
        #pragma unroll
        for (int tn = 0; tn < 2; ++tn)
            acc[mt][tn] = (v4f){0.f, 0.f, 0.f, 0.f};

    #pragma unroll
    for (int ks = 0; ks < 4; ++ks) {
        const int c = ks * 4 + quad;    // k-chunk index; k = c*8 + e
        v8s ah[4], al[4], bh[2], bl[2];
        #pragma unroll
        for (int mt = 0; mt < 4; ++mt) {
            const size_t ai = ((size_t)c * P + (p0 + mt * 16 + l16)) * 8;
            ah[mt] = *(const v8s*)&Yhi[ai];
            al[mt] = *(const v8s*)&Ylo[ai];
        }
        #pragma unroll
        for (int tn = 0; tn < 2; ++tn) {
            const size_t bi = ((size_t)c * 1024 + (h0 + wn * 32 + tn * 16 + l16)) * 8;
            bh[tn] = *(const v8s*)&Whi[bi];
            bl[tn] = *(const v8s*)&Wlo[bi];
        }
        #pragma unroll
        for (int mt = 0; mt < 4; ++mt)
            #pragma unroll
            for (int tn = 0; tn < 2; ++tn) {
                acc[mt][tn] = __builtin_amdgcn_mfma_f32_16x16x32_bf16(ah[mt], bh[tn], acc[mt][tn], 0, 0, 0);
                acc[mt][tn] = __builtin_amdgcn_mfma_f32_16x16x32_bf16(ah[mt], bl[tn], acc[mt][tn], 0, 0, 0);
                acc[mt][tn] = __builtin_amdgcn_mfma_f32_16x16x32_bf16(al[mt], bh[tn], acc[mt][tn], 0, 0, 0);
            }
    }

    // epilogue: + bias + exact fp32 rank-1 for k=128
    #pragma unroll
    for (int tn = 0; tn < 2; ++tn) {
        const int hc = wn * 32 + tn * 16 + l16;
        const float bv = bias[h0 + hc];
        const float wv = w128c[h0 + hc];
        #pragma unroll
        for (int mt = 0; mt < 4; ++mt) {
            const v4f yv = *(const v4f*)&y128[p0 + mt * 16 + quad * 4];
            #pragma unroll
            for (int i = 0; i < 4; ++i) {
                const int row = mt * 16 + quad * 4 + i;
                out[(size_t)(p0 + row) * 1024 + (h0 + hc)] = acc[mt][tn][i] + bv + yv[i] * wv;
            }
        }
    }
}

// ======================================================================
// Fallback: previous fused kernel (used only if workspace too small).
// ======================================================================
__global__ __launch_bounds__(512, 2)
void sph_mfma(const float* __restrict__ x, const float* __restrict__ W,
              const float* __restrict__ bias, float* __restrict__ out) {
    __shared__ alignas(16) unsigned short Yhi[128 * KP];
    __shared__ alignas(16) unsigned short Ylo[128 * KP];
    __shared__ alignas(16) unsigned short Whi[128 * KP];
    __shared__ alignas(16) unsigned short Wlo[128 * KP];
    __shared__ float y128[128];
    __shared__ float w128[128];

    const int tid = threadIdx.x;
    const int p0 = blockIdx.x * 128;
    const int h0 = blockIdx.y * 128;

    {
        const int r  = tid >> 2;
        const int cp = tid & 3;
        const float* wrow = W + (size_t)(h0 + r) * 129;
        #pragma unroll
        for (int i = 0; i < 33; ++i) {
            const int k = cp + 4 * i;
            if (k < 128) {
                const float w = wrow[k];
                float hf;
                Whi[r * KP + k] = bf16_rne(w, &hf);
                float dummy;
                Wlo[r * KP + k] = bf16_rne(w - hf, &dummy);
            } else if (k == 128) {
                w128[r] = wrow[128];
            }
        }
    }

    {
        const int pix = tid & 127;
        const int s   = tid >> 7;
        const int m0  = 16 * s;
        const float2 tp = *(const float2*)&x[(size_t)(p0 + pix) * 2];
        const float theta = tp.x, phi = tp.y;

        const float ct = cosf(phi);
        const float st = sqrtf(fmaxf(1.0f - ct * ct, 0.0f));

        float prod = 1.0f;
        for (int i = 1; i <= m0; ++i) prod *= (2.0f * i + 1.0f) / (2.0f * i);
        const float s2 = st * st, s4 = s2 * s2, s8 = s4 * s4, s16 = s8 * s8;
        float stp = 1.0f;
        for (int i = 0; i < s; ++i) stp *= s16;
        float pm = 0.28209479177387814f * sqrtf(prod) * stp;

        float cm, sm, c1, s1;
        sincosf((float)m0 * theta, &sm, &cm);
        sincosf(theta, &s1, &c1);

        if (s == 0) {
            const float y0 = 1.7320508075688772f * ct * pm;
            float hf, d;
            Yhi[pix * KP + 64] = bf16_rne(y0, &hf);
            Ylo[pix * KP + 64] = bf16_rne(y0 - hf, &d);
        }

        #pragma unroll
        for (int j = 1; j <= 16; ++j) {
            const int m = m0 + j;
            pm *= -sqrtf((2.0f * m + 1.0f) / (2.0f * m)) * st;
            const float cn = cm * c1 - sm * s1;
            const float sn = sm * c1 + cm * s1;
            cm = cn; sm = sn;
            const float yb = sqrtf(2.0f * m + 3.0f) * ct * pm;
            const float t  = (m & 1) ? -1.4142135623730951f : 1.4142135623730951f;
            const float vp = t * yb * cm;
            const float vn = t * yb * sm;
            {
                float hf, d;
                const int kn = 64 - m;
                Yhi[pix * KP + kn] = bf16_rne(vn, &hf);
                Ylo[pix * KP + kn] = bf16_rne(vn - hf, &d);
            }
            const int kp = 64 + m;
            if (kp < 128) {
                float hf, d;
                Yhi[pix * KP + kp] = bf16_rne(vp, &hf);
                Ylo[pix * KP + kp] = bf16_rne(vp - hf, &d);
            } else {
                y128[pix] = vp;
            }
        }
    }
    __syncthreads();

    const int lane = tid & 63;
    const int wid  = tid >> 6;
    const int wm   = wid & 1;
    const int wn   = wid >> 1;
    const int l16  = lane & 15;
    const int quad = lane >> 4;

    const int arow0 = wm * 64 + l16;
    const int brow0 = wn * 32 + l16;

    v4f acc[4][2];
    #pragma unroll
    for (int mt = 0; mt < 4; ++mt)
        #pragma unroll
        for (int tn = 0; tn < 2; ++tn)
            acc[mt][tn] = (v4f){0.f, 0.f, 0.f, 0.f};

    #pragma unroll
    for (int ks = 0; ks < 4; ++ks) {
        const int ko = ks * 32 + quad * 8;
        v8s ah[4], al[4], bh[2], bl[2];
        #pragma unroll
        for (int mt = 0; mt < 4; ++mt) {
            ah[mt] = *(const v8s*)&Yhi[(arow0 + mt * 16) * KP + ko];
            al[mt] = *(const v8s*)&Ylo[(arow0 + mt * 16) * KP + ko];
        }
        #pragma unroll
        for (int tn = 0; tn < 2; ++tn) {
            bh[tn] = *(const v8s*)&Whi[(brow0 + tn * 16) * KP + ko];
            bl[tn] = *(const v8s*)&Wlo[(brow0 + tn * 16) * KP + ko];
        }
        #pragma unroll
        for (int mt = 0; mt < 4; ++mt)
            #pragma unroll
            for (int tn = 0; tn < 2; ++tn) {
                acc[mt][tn] = __builtin_amdgcn_mfma_f32_16x16x32_bf16(ah[mt], bh[tn], acc[mt][tn], 0, 0, 0);
                acc[mt][tn] = __builtin_amdgcn_mfma_f32_16x16x32_bf16(ah[mt], bl[tn], acc[mt][tn], 0, 0, 0);
                acc[mt][tn] = __builtin_amdgcn_mfma_f32_16x16x32_bf16(al[mt], bh[tn], acc[mt][tn], 0, 0, 0);
            }
    }

    #pragma unroll
    for (int tn = 0; tn < 2; ++tn) {
        const int hc = wn * 32 + tn * 16 + l16;
        const float bv = bias[h0 + hc];
        const float wv = w128[hc];
        #pragma unroll
        for (int mt = 0; mt < 4; ++mt) {
            #pragma unroll
            for (int i = 0; i < 4; ++i) {
                const int row = wm * 64 + mt * 16 + quad * 4 + i;
                const float o = acc[mt][tn][i] + bv + y128[row] * wv;
                out[(size_t)(p0 + row) * 1024 + (h0 + hc)] = o;
            }
        }
    }
}

extern "C" void kernel_launch(void* const* d_in, const int* in_sizes, int n_in,
                              void* d_out, int out_size, void* d_ws, size_t ws_size,
                              hipStream_t stream) {
    const float* x = (const float*)d_in[0];   // (4,128,256,1,2) -> 131072 pixels
    const float* W = (const float*)d_in[1];   // (1024,129)
    const float* b = (const float*)d_in[2];   // (1024,)
    float* out = (float*)d_out;               // (131072,1024)

    const int P = in_sizes[0] / 2;

    const size_t szY   = (size_t)16 * (size_t)P * 8 * sizeof(unsigned short); // 32 MiB @ P=131072
    const size_t szy128 = (size_t)P * sizeof(float);
    const size_t szW   = (size_t)16 * 1024 * 8 * sizeof(unsigned short);      // 256 KiB
    const size_t szw128 = 1024 * sizeof(float);
    const size_t need = 2 * szY + szy128 + 2 * szW + szw128;

    if (d_ws != nullptr && ws_size >= need) {
        char* base = (char*)d_ws;
        unsigned short* Yhi = (unsigned short*)(base);
        unsigned short* Ylo = (unsigned short*)(base + szY);
        float*          y128 = (float*)(base + 2 * szY);
        unsigned short* Whi = (unsigned short*)(base + 2 * szY + szy128);
        unsigned short* Wlo = (unsigned short*)(base + 2 * szY + szy128 + szW);
        float*          w128c = (float*)(base + 2 * szY + szy128 + 2 * szW);

        const int nyb = P / 128;               // 1024 Y blocks
        sph_prep<<<dim3(nyb + 32), dim3(512), 0, stream>>>(x, W, Yhi, Ylo, y128, Whi, Wlo, w128c, P);
        sph_gemm<<<dim3(P / 64, 8), dim3(256), 0, stream>>>(Yhi, Ylo, y128, Whi, Wlo, w128c, b, out, P);
    } else {
        dim3 grid(P / 128, 1024 / 128);
        sph_mfma<<<grid, dim3(512), 0, stream>>>(x, W, b, out);
    }
}

// Round 2
// 631.904 us; speedup vs baseline: 1.6360x; 1.1547x over previous
//
#include <hip/hip_runtime.h>
#include <math.h>

#define KP 136   // padded K stride in LDS (elements) for fallback kernel

typedef short v8s __attribute__((ext_vector_type(8)));
typedef float v4f __attribute__((ext_vector_type(4)));

// round-to-nearest-even float -> bf16 bits; also returns the bf16 value as float
__device__ __forceinline__ unsigned short bf16_rne(float f, float* back) {
    union { float f; unsigned u; } a; a.f = f;
    unsigned r = a.u + 0x7FFFu + ((a.u >> 16) & 1u);
    unsigned short h = (unsigned short)(r >> 16);
    union { unsigned u; float f; } bb; bb.u = (unsigned)h << 16;
    *back = bb.f;
    return h;
}

// ======================================================================
// Kernel 1 (sph_prep): compute Y once, store split-bf16 in MFMA-fragment
// chunk layout [c][P][8] (k = c*8+e). Convert W once into [c][1024][8].
// Kernel 2 (sph_gemm): persistent-A GEMM. Each block owns 32 pixels and
// ALL 1024 channels (h-loop of 8 x 128-ch tiles inside). A (Y) fragments
// K-resident in registers (loaded once); B (W) double-buffered one
// K-step ahead from L2. No LDS, no barriers. 3 waves/SIMD.
// ======================================================================

__global__ __launch_bounds__(512)
void sph_prep(const float* __restrict__ x, const float* __restrict__ W,
              unsigned short* __restrict__ Yhi, unsigned short* __restrict__ Ylo,
              float* __restrict__ y128,
              unsigned short* __restrict__ Whi, unsigned short* __restrict__ Wlo,
              float* __restrict__ w128c, int P) {
    const int tid = threadIdx.x;
    const int nyb = P >> 7;                 // pixel blocks (128 pixels each)
    const int b = blockIdx.x;

    if (b < nyb) {
        // ---- Y part: thread = (pixel, segment s). Segment s covers
        // recurrence m = 16s .. 16s+16; writes pos k = 64+16s..79+16s
        // (chunks 8+2s, 9+2s) and neg k = 48-16s..63-16s (chunks 6-2s, 7-2s).
        const int pix = tid & 127;
        const int s   = tid >> 7;           // uniform per wave
        const int m0  = 16 * s;
        const int p   = b * 128 + pix;
        const float2 tp = *(const float2*)&x[(size_t)p * 2];
        const float theta = tp.x, phi = tp.y;

        const float ct = cosf(phi);
        const float st = sqrtf(fmaxf(1.0f - ct * ct, 0.0f));

        // jump-start Pbar_{m0}^{m0}
        float prod = 1.0f;
        for (int i = 1; i <= m0; ++i) prod *= (2.0f * i + 1.0f) / (2.0f * i);
        const float s2_ = st * st, s4 = s2_ * s2_, s8 = s4 * s4, s16 = s8 * s8;
        float stp = 1.0f;
        for (int i = 0; i < s; ++i) stp *= s16;
        float pm = 0.28209479177387814f * sqrtf(prod) * stp;

        float cm, sm, c1, s1;
        sincosf((float)m0 * theta, &sm, &cm);
        sincosf(theta, &s1, &c1);

        unsigned short ph[16], pl[16], nh[16], nl[16];
        float y128v = 0.0f;

        // j = 0 (m = m0): pos k = 64 + m0
        {
            const float yb = sqrtf(2.0f * m0 + 3.0f) * ct * pm;
            const float val = (s == 0) ? yb                       // m=0: no sqrt2, cos0=1
                                       : 1.4142135623730951f * yb * cm;  // m0 even -> +
            float hf, d;
            ph[0] = bf16_rne(val, &hf);
            pl[0] = bf16_rne(val - hf, &d);
        }

        #pragma unroll
        for (int j = 1; j <= 16; ++j) {
            const int m = m0 + j;
            pm *= -sqrtf((2.0f * m + 1.0f) / (2.0f * m)) * st;
            const float cn = cm * c1 - sm * s1;
            const float sn = sm * c1 + cm * s1;
            cm = cn; sm = sn;
            const float yb = sqrtf(2.0f * m + 3.0f) * ct * pm;
            const float t  = (m & 1) ? -1.4142135623730951f : 1.4142135623730951f;
            const float vp = t * yb * cm;   // k = 64 + m
            const float vn = t * yb * sm;   // k = 64 - m
            {
                float hf, d;
                nh[16 - j] = bf16_rne(vn, &hf);       // neg idx i = k-(48-16s) = 16-j
                nl[16 - j] = bf16_rne(vn - hf, &d);
            }
            if (j <= 15) {
                float hf, d;
                ph[j] = bf16_rne(vp, &hf);
                pl[j] = bf16_rne(vp - hf, &d);
            } else if (s == 3) {
                y128v = vp;                           // m = 64 -> k = 128
            }
            // (for s<3, j=16 pos value k=80+16s is produced by segment s+1's j=0)
        }

        // ---- coalesced chunk stores: addr (c*P + p)*8 elems; lanes = consecutive p
        {
            v8s vh, vl;
            #pragma unroll
            for (int e = 0; e < 8; ++e) { vh[e] = (short)ph[e]; vl[e] = (short)pl[e]; }
            *(v8s*)&Yhi[((size_t)(8 + 2 * s) * P + p) * 8] = vh;
            *(v8s*)&Ylo[((size_t)(8 + 2 * s) * P + p) * 8] = vl;
        }
        {
            v8s vh, vl;
            #pragma unroll
            for (int e = 0; e < 8; ++e) { vh[e] = (short)ph[8 + e]; vl[e] = (short)pl[8 + e]; }
            *(v8s*)&Yhi[((size_t)(9 + 2 * s) * P + p) * 8] = vh;
            *(v8s*)&Ylo[((size_t)(9 + 2 * s) * P + p) * 8] = vl;
        }
        {
            v8s vh, vl;
            #pragma unroll
            for (int e = 0; e < 8; ++e) { vh[e] = (short)nh[e]; vl[e] = (short)nl[e]; }
            *(v8s*)&Yhi[((size_t)(6 - 2 * s) * P + p) * 8] = vh;
            *(v8s*)&Ylo[((size_t)(6 - 2 * s) * P + p) * 8] = vl;
        }
        {
            v8s vh, vl;
            #pragma unroll
            for (int e = 0; e < 8; ++e) { vh[e] = (short)nh[8 + e]; vl[e] = (short)nl[8 + e]; }
            *(v8s*)&Yhi[((size_t)(7 - 2 * s) * P + p) * 8] = vh;
            *(v8s*)&Ylo[((size_t)(7 - 2 * s) * P + p) * 8] = vl;
        }
        if (s == 3) y128[p] = y128v;
    } else {
        // ---- W part: one thread per (h, c); 16384 threads = 32 blocks
        const int idx = (b - nyb) * 512 + tid;
        const int c = idx >> 10;
        const int h = idx & 1023;
        const float* wrow = W + (size_t)h * 129 + c * 8;
        v8s vh, vl;
        #pragma unroll
        for (int e = 0; e < 8; ++e) {
            const float w = wrow[e];
            float hf, d;
            vh[e] = (short)bf16_rne(w, &hf);
            vl[e] = (short)bf16_rne(w - hf, &d);
        }
        *(v8s*)&Whi[((size_t)c * 1024 + h) * 8] = vh;
        *(v8s*)&Wlo[((size_t)c * 1024 + h) * 8] = vl;
        if (idx < 1024) w128c[idx] = W[(size_t)idx * 129 + 128];
    }
}

// Persistent-A GEMM: block = 32 pixels x 1024 channels (8 h-tiles of 128).
// 4 waves (wn = channel quarter within h-tile). A K-resident; B dbuf'd.
__global__ __launch_bounds__(256, 3)
void sph_gemm(const unsigned short* __restrict__ Yhi, const unsigned short* __restrict__ Ylo,
              const float* __restrict__ y128,
              const unsigned short* __restrict__ Whi, const unsigned short* __restrict__ Wlo,
              const float* __restrict__ w128c, const float* __restrict__ bias,
              float* __restrict__ out, int P) {
    const int tid  = threadIdx.x;
    const int lane = tid & 63;
    const int wn   = tid >> 6;          // 0..3 -> 32 channels within each 128-ch tile
    const int l16  = lane & 15;
    const int quad = lane >> 4;
    const int p0 = blockIdx.x * 32;     // pixel tile origin

    // ---- load ALL A fragments once: 32 px x 128 k, hi+lo (64 VGPR) ----
    v8s ah[2][4], al[2][4];             // [mt][ks]; k-chunk c = ks*4 + quad
    #pragma unroll
    for (int ks = 0; ks < 4; ++ks) {
        const int c = ks * 4 + quad;
        #pragma unroll
        for (int mt = 0; mt < 2; ++mt) {
            const size_t ai = ((size_t)c * P + (p0 + mt * 16 + l16)) * 8;
            ah[mt][ks] = *(const v8s*)&Yhi[ai];
            al[mt][ks] = *(const v8s*)&Ylo[ai];
        }
    }
    // exact fp32 k=128 column, per-lane rows
    v4f yv[2];
    #pragma unroll
    for (int mt = 0; mt < 2; ++mt)
        yv[mt] = *(const v4f*)&y128[p0 + mt * 16 + quad * 4];

    const int bcol = wn * 32 + l16;     // + tn*16 within 128-ch tile

    // ---- B double buffer, one K-step ahead ----
    v8s bh[2][2], bl[2][2];             // [parity][tn]
    #pragma unroll
    for (int tn = 0; tn < 2; ++tn) {    // prefetch step 0: h=0, ks=0 -> c=quad
        const size_t bi = ((size_t)quad * 1024 + bcol + tn * 16) * 8;
        bh[0][tn] = *(const v8s*)&Whi[bi];
        bl[0][tn] = *(const v8s*)&Wlo[bi];
    }

    #pragma unroll
    for (int h = 0; h < 8; ++h) {
        v4f acc[2][2];
        #pragma unroll
        for (int mt = 0; mt < 2; ++mt)
            #pragma unroll
            for (int tn = 0; tn < 2; ++tn)
                acc[mt][tn] = (v4f){0.f, 0.f, 0.f, 0.f};

        #pragma unroll
        for (int ks = 0; ks < 4; ++ks) {
            const int step = h * 4 + ks;
            const int par  = step & 1;
            if (step + 1 < 32) {        // prefetch next K-step's B tile
                const int ns  = step + 1;
                const int nh  = ns >> 2;
                const int nc  = (ns & 3) * 4 + quad;
                #pragma unroll
                for (int tn = 0; tn < 2; ++tn) {
                    const size_t bi = ((size_t)nc * 1024 + nh * 128 + bcol + tn * 16) * 8;
                    bh[par ^ 1][tn] = *(const v8s*)&Whi[bi];
                    bl[par ^ 1][tn] = *(const v8s*)&Wlo[bi];
                }
            }
            #pragma unroll
            for (int mt = 0; mt < 2; ++mt)
                #pragma unroll
                for (int tn = 0; tn < 2; ++tn) {
                    acc[mt][tn] = __builtin_amdgcn_mfma_f32_16x16x32_bf16(ah[mt][ks], bh[par][tn], acc[mt][tn], 0, 0, 0);
                    acc[mt][tn] = __builtin_amdgcn_mfma_f32_16x16x32_bf16(ah[mt][ks], bl[par][tn], acc[mt][tn], 0, 0, 0);
                    acc[mt][tn] = __builtin_amdgcn_mfma_f32_16x16x32_bf16(al[mt][ks], bh[par][tn], acc[mt][tn], 0, 0, 0);
                }
        }

        // ---- epilogue for this 128-ch tile: bias + exact k=128 rank-1 ----
        float bv[2], wv[2];
        #pragma unroll
        for (int tn = 0; tn < 2; ++tn) {
            bv[tn] = bias[h * 128 + bcol + tn * 16];
            wv[tn] = w128c[h * 128 + bcol + tn * 16];
        }
        #pragma unroll
        for (int mt = 0; mt < 2; ++mt)
            #pragma unroll
            for (int i = 0; i < 4; ++i) {
                const int row = mt * 16 + quad * 4 + i;
                float* orow = out + (size_t)(p0 + row) * 1024 + h * 128;
                // paired 64B halves of the same 128B line, back-to-back
                orow[bcol]      = acc[mt][0][i] + bv[0] + yv[mt][i] * wv[0];
                orow[bcol + 16] = acc[mt][1][i] + bv[1] + yv[mt][i] * wv[1];
            }
    }
}

// ======================================================================
// Fallback: previous fused kernel (used only if workspace too small).
// ======================================================================
__global__ __launch_bounds__(512, 2)
void sph_mfma(const float* __restrict__ x, const float* __restrict__ W,
              const float* __restrict__ bias, float* __restrict__ out) {
    __shared__ alignas(16) unsigned short Yhi[128 * KP];
    __shared__ alignas(16) unsigned short Ylo[128 * KP];
    __shared__ alignas(16) unsigned short Whi[128 * KP];
    __shared__ alignas(16) unsigned short Wlo[128 * KP];
    __shared__ float y128[128];
    __shared__ float w128[128];

    const int tid = threadIdx.x;
    const int p0 = blockIdx.x * 128;
    const int h0 = blockIdx.y * 128;

    {
        const int r  = tid >> 2;
        const int cp = tid & 3;
        const float* wrow = W + (size_t)(h0 + r) * 129;
        #pragma unroll
        for (int i = 0; i < 33; ++i) {
            const int k = cp + 4 * i;
            if (k < 128) {
                const float w = wrow[k];
                float hf;
                Whi[r * KP + k] = bf16_rne(w, &hf);
                float dummy;
                Wlo[r * KP + k] = bf16_rne(w - hf, &dummy);
            } else if (k == 128) {
                w128[r] = wrow[128];
            }
        }
    }

    {
        const int pix = tid & 127;
        const int s   = tid >> 7;
        const int m0  = 16 * s;
        const float2 tp = *(const float2*)&x[(size_t)(p0 + pix) * 2];
        const float theta = tp.x, phi = tp.y;

        const float ct = cosf(phi);
        const float st = sqrtf(fmaxf(1.0f - ct * ct, 0.0f));

        float prod = 1.0f;
        for (int i = 1; i <= m0; ++i) prod *= (2.0f * i + 1.0f) / (2.0f * i);
        const float s2 = st * st, s4 = s2 * s2, s8 = s4 * s4, s16 = s8 * s8;
        float stp = 1.0f;
        for (int i = 0; i < s; ++i) stp *= s16;
        float pm = 0.28209479177387814f * sqrtf(prod) * stp;

        float cm, sm, c1, s1;
        sincosf((float)m0 * theta, &sm, &cm);
        sincosf(theta, &s1, &c1);

        if (s == 0) {
            const float y0 = 1.7320508075688772f * ct * pm;
            float hf, d;
            Yhi[pix * KP + 64] = bf16_rne(y0, &hf);
            Ylo[pix * KP + 64] = bf16_rne(y0 - hf, &d);
        }

        #pragma unroll
        for (int j = 1; j <= 16; ++j) {
            const int m = m0 + j;
            pm *= -sqrtf((2.0f * m + 1.0f) / (2.0f * m)) * st;
            const float cn = cm * c1 - sm * s1;
            const float sn = sm * c1 + cm * s1;
            cm = cn; sm = sn;
            const float yb = sqrtf(2.0f * m + 3.0f) * ct * pm;
            const float t  = (m & 1) ? -1.4142135623730951f : 1.4142135623730951f;
            const float vp = t * yb * cm;
            const float vn = t * yb * sm;
            {
                float hf, d;
                const int kn = 64 - m;
                Yhi[pix * KP + kn] = bf16_rne(vn, &hf);
                Ylo[pix * KP + kn] = bf16_rne(vn - hf, &d);
            }
            const int kp = 64 + m;
            if (kp < 128) {
                float hf, d;
                Yhi[pix * KP + kp] = bf16_rne(vp, &hf);
                Ylo[pix * KP + kp] = bf16_rne(vp - hf, &d);
            } else {
                y128[pix] = vp;
            }
        }
    }
    __syncthreads();

    const int lane = tid & 63;
    const int wid  = tid >> 6;
    const int wm   = wid & 1;
    const int wn   = wid >> 1;
    const int l16  = lane & 15;
    const int quad = lane >> 4;

    const int arow0 = wm * 64 + l16;
    const int brow0 = wn * 32 + l16;

    v4f acc[4][2];
    #pragma unroll
    for (int mt = 0; mt < 4; ++mt)
        #pragma unroll
        for (int tn = 0; tn < 2; ++tn)
            acc[mt][tn] = (v4f){0.f, 0.f, 0.f, 0.f};

    #pragma unroll
    for (int ks = 0; ks < 4; ++ks) {
        const int ko = ks * 32 + quad * 8;
        v8s ah[4], al[4], bh[2], bl[2];
        #pragma unroll
        for (int mt = 0; mt < 4; ++mt) {
            ah[mt] = *(const v8s*)&Yhi[(arow0 + mt * 16) * KP + ko];
            al[mt] = *(const v8s*)&Ylo[(arow0 + mt * 16) * KP + ko];
        }
        #pragma unroll
        for (int tn = 0; tn < 2; ++tn) {
            bh[tn] = *(const v8s*)&Whi[(brow0 + tn * 16) * KP + ko];
            bl[tn] = *(const v8s*)&Wlo[(brow0 + tn * 16) * KP + ko];
        }
        #pragma unroll
        for (int mt = 0; mt < 4; ++mt)
            #pragma unroll
            for (int tn = 0; tn < 2; ++tn) {
                acc[mt][tn] = __builtin_amdgcn_mfma_f32_16x16x32_bf16(ah[mt], bh[tn], acc[mt][tn], 0, 0, 0);
                acc[mt][tn] = __builtin_amdgcn_mfma_f32_16x16x32_bf16(ah[mt], bl[tn], acc[mt][tn], 0, 0, 0);
                acc[mt][tn] = __builtin_amdgcn_mfma_f32_16x16x32_bf16(al[mt], bh[tn], acc[mt][tn], 0, 0, 0);
            }
    }

    #pragma unroll
    for (int tn = 0; tn < 2; ++tn) {
        const int hc = wn * 32 + tn * 16 + l16;
        const float bv = bias[h0 + hc];
        const float wv = w128[hc];
        #pragma unroll
        for (int mt = 0; mt < 4; ++mt) {
            #pragma unroll
            for (int i = 0; i < 4; ++i) {
                const int row = wm * 64 + mt * 16 + quad * 4 + i;
                const float o = acc[mt][tn][i] + bv + y128[row] * wv;
                out[(size_t)(p0 + row) * 1024 + (h0 + hc)] = o;
            }
        }
    }
}

extern "C" void kernel_launch(void* const* d_in, const int* in_sizes, int n_in,
                              void* d_out, int out_size, void* d_ws, size_t ws_size,
                              hipStream_t stream) {
    const float* x = (const float*)d_in[0];   // (4,128,256,1,2) -> 131072 pixels
    const float* W = (const float*)d_in[1];   // (1024,129)
    const float* b = (const float*)d_in[2];   // (1024,)
    float* out = (float*)d_out;               // (131072,1024)

    const int P = in_sizes[0] / 2;

    const size_t szY   = (size_t)16 * (size_t)P * 8 * sizeof(unsigned short); // 32 MiB @ P=131072
    const size_t szy128 = (size_t)P * sizeof(float);
    const size_t szW   = (size_t)16 * 1024 * 8 * sizeof(unsigned short);      // 256 KiB
    const size_t szw128 = 1024 * sizeof(float);
    const size_t need = 2 * szY + szy128 + 2 * szW + szw128;

    if (d_ws != nullptr && ws_size >= need) {
        char* base = (char*)d_ws;
        unsigned short* Yhi = (unsigned short*)(base);
        unsigned short* Ylo = (unsigned short*)(base + szY);
        float*          y128 = (float*)(base + 2 * szY);
        unsigned short* Whi = (unsigned short*)(base + 2 * szY + szy128);
        unsigned short* Wlo = (unsigned short*)(base + 2 * szY + szy128 + szW);
        float*          w128c = (float*)(base + 2 * szY + szy128 + 2 * szW);

        const int nyb = P / 128;               // 1024 Y blocks
        sph_prep<<<dim3(nyb + 32), dim3(512), 0, stream>>>(x, W, Yhi, Ylo, y128, Whi, Wlo, w128c, P);
        sph_gemm<<<dim3(P / 32), dim3(256), 0, stream>>>(Yhi, Ylo, y128, Whi, Wlo, w128c, b, out, P);
    } else {
        dim3 grid(P / 128, 1024 / 128);
        sph_mfma<<<grid, dim3(512), 0, stream>>>(x, W, b, out);
    }
}